// Round 11
// baseline (541.074 us; speedup 1.0000x reference)
//
#include <hip/hip_runtime.h>
#include <hip/hip_bf16.h>

typedef __attribute__((ext_vector_type(8))) short short8;
typedef __attribute__((ext_vector_type(4))) float f32x4;
typedef unsigned char u8;

#define DEV static __device__ __forceinline__

// branchless A&S erf gelu; one __expf(-x^2/2) serves erf tail + pdf term
DEV void gelu_pair(float x, float& z, float& dz){
  float ax = fabsf(x)*0.70710678118654752f;
  float e  = __expf(-ax*ax);
  float t  = __fdividef(1.0f, 1.0f + 0.3275911f*ax);
  float poly = t*(0.254829592f + t*(-0.284496736f + t*(1.421413741f +
               t*(-1.453152027f + t*1.061405429f))));
  float erfv = 1.0f - poly*e;
  erfv = x < 0.0f ? -erfv : erfv;
  float cdf = 0.5f*(1.0f + erfv);
  z  = x*cdf;
  dz = cdf + x*0.39894228040143268f*e;
}
DEV float dgelu_f(float x){ float zz, dz; gelu_pair(x, zz, dz); return dz; }
DEV float softplus_f(float x){ return log1pf(expf(x)); }
DEV void store_f4_a4(float* p, f32x4 v){ __builtin_memcpy(p, &v, 16); }

DEV void gload_lds16(const __hip_bfloat16* g, __hip_bfloat16* l){
  __builtin_amdgcn_global_load_lds((const __attribute__((address_space(1))) void*)g,
                                   (__attribute__((address_space(3))) void*)l, 16, 0, 0);
}

// fp8 e4m3 (gfx950 OCP) encode via HW cvt — same HW format the fp8 MFMA consumes
DEV u8 f2fp8(float f){
  int r = __builtin_amdgcn_cvt_pk_fp8_f32(f, f, 0, false);
  return (u8)(r & 0xff);
}
DEV unsigned pk4_fp8(float a, float b, float c, float d){
  int r = __builtin_amdgcn_cvt_pk_fp8_f32(a, b, 0, false);
  r = __builtin_amdgcn_cvt_pk_fp8_f32(c, d, r, true);
  return (unsigned)r;
}

DEV unsigned pack2bf(float a, float b){
  __hip_bfloat16 ba = __float2bfloat16(a), bb = __float2bfloat16(b);
  unsigned short ua, ub;
  __builtin_memcpy(&ua, &ba, 2); __builtin_memcpy(&ub, &bb, 2);
  return (unsigned)ua | ((unsigned)ub << 16);
}
DEV float unp_lo(unsigned u){ union{unsigned x; float f;} c; c.x = u << 16; return c.f; }
DEV float unp_hi(unsigned u){ union{unsigned x; float f;} c; c.x = u & 0xffff0000u; return c.f; }

// stream scales (exact powers of 2): encode value*S into fp8, decode by folding
// 1/(Sa*Sw) into the epilogue.
#define SW    32.0f
#define SZC   32.0f
#define SZ1   256.0f
#define SZ2   1024.0f
#define SG3   256.0f
#define INV1  (1.0f/1024.0f)
#define INV2  (1.0f/8192.0f)
#define INV3  (1.0f/32768.0f)
#define EN4   0.125f
#define EN5   0.125f
#define INV6  (1.0f/131072.0f)

// ---------------- embed: h = E[x] + P, S = 16-row chunk sums (v implicit 0 at layer 0) ----------------
__global__ __launch_bounds__(512) void embed_k(const int* __restrict__ x,
                        const float* __restrict__ E, const float* __restrict__ P,
                        float* __restrict__ h, float* __restrict__ S){
  int bid = blockIdx.x;
  int row = threadIdx.x >> 5;
  int q   = threadIdx.x & 31;
  int tok = bid*16 + row;
  int t   = tok & 511;
  int id  = x[tok];
  float4 e4 = ((const float4*)E)[(size_t)id*32 + q];
  float4 p4 = ((const float4*)P)[(size_t)t*32 + q];
  float4 val; val.x=e4.x+p4.x; val.y=e4.y+p4.y; val.z=e4.z+p4.z; val.w=e4.w+p4.w;
  ((float4*)h)[(size_t)tok*32 + q] = val;
  __shared__ float4 ps[16][32];
  ps[row][q] = val;
  __syncthreads();
  if (row==0){
    float4 s = ps[0][q];
    #pragma unroll
    for (int r=1;r<16;r++){
      float4 t4 = ps[r][q];
      s.x+=t4.x; s.y+=t4.y; s.z+=t4.z; s.w+=t4.w;
    }
    ((float4*)S)[(size_t)bid*32 + q] = s;
  }
}

// ---------------- weight pre-tiling into MFMA B-fragment order, fp8 e4m3 ----------------
// layout: Wt[(k>>3)*N*8 + n*8 + (k&7)] = fp8(SW * W_logical[n][k])
__global__ void convw_k(const float* __restrict__ W0, const float* __restrict__ W1,
                        const float* __restrict__ W2,
                        u8* __restrict__ W0T, u8* __restrict__ W1T,
                        u8* __restrict__ W2T, u8* __restrict__ W2b,
                        u8* __restrict__ W1b, u8* __restrict__ W0h){
  int i = blockIdx.x*256 + threadIdx.x;
  if (i < 131072){                     // W0T: B[n][k]=W0[k][n], K=256
    int e=i&7, n=(i>>3)&511, kk=i>>12; int k=(kk>>2)*32+(kk&3)*8+e;
    W0T[i]=f2fp8(SW*W0[(size_t)k*512+n]);
  } else if (i < 393216){              // W1T
    int j=i-131072; int e=j&7, n=(j>>3)&511, kk=j>>12; int k=(kk>>2)*32+(kk&3)*8+e;
    W1T[j]=f2fp8(SW*W1[(size_t)k*512+n]);
  } else if (i < 655360){              // W2T
    int j=i-393216; int e=j&7, n=(j>>3)&511, kk=j>>12; int k=(kk>>2)*32+(kk&3)*8+e;
    W2T[j]=f2fp8(SW*W2[(size_t)k*512+n]);
  } else if (i < 917504){              // W2b: B[n][k]=W2[n][k]
    int j=i-655360; int e=j&7, n=(j>>3)&511, kk=j>>12; int k=(kk>>2)*32+(kk&3)*8+e;
    W2b[j]=f2fp8(SW*W2[(size_t)n*512+k]);
  } else if (i < 1179648){             // W1b
    int j=i-917504; int e=j&7, n=(j>>3)&511, kk=j>>12; int k=(kk>>2)*32+(kk&3)*8+e;
    W1b[j]=f2fp8(SW*W1[(size_t)n*512+k]);
  } else if (i < 1245184){             // W0h: B[d][k]=W0[128+d][k], N=128
    int j=i-1179648; int e=j&7, n=(j>>3)&127, kk=j>>10; int k=(kk>>2)*32+(kk&3)*8+e;
    W0h[j]=f2fp8(SW*W0[(size_t)(128+n)*512+k]);
  }
}
__global__ void conv_c4_k(const float* __restrict__ W, __hip_bfloat16* __restrict__ Wb, int n4){
  int i = blockIdx.x*256 + threadIdx.x;
  if (i < n4){
    float4 f = ((const float4*)W)[i];
    Wb[4*i+0]=__float2bfloat16(f.x);
    Wb[4*i+1]=__float2bfloat16(f.y);
    Wb[4*i+2]=__float2bfloat16(f.z);
    Wb[4*i+3]=__float2bfloat16(f.w);
  }
}

// ---------------- fused layer kernel, M-tile 16, 1024 threads (4 waves/SIMD) ----------------
struct LayerP {
  const u8 *W0T,*W1T,*W2T,*W2b,*W1b,*W0h;
  const float *b0,*b1,*b2,*W3;
  float *v, *h; __hip_bfloat16* hbf;
  const float* Sprev; float* Snext;
  const float *rawm,*rawg;
  int first, last;
};

// depth-5 / mod-6 ring prefetch; K-rotation de-phases the 32 CUs sharing an XCD.
template<int KSTEPS, int NW, int NF>
DEV void wpre(const u8* __restrict__ Wt, int nbase, int r16, int g, int rot,
              long (&bb)[6][NF]){
  const u8* wp = Wt + ((size_t)g*NW + nbase + r16)*8;
  #pragma unroll
  for (int d=0; d<5; d++){
    if (d < KSTEPS){
      int dd = (d + rot) & (KSTEPS-1);
      #pragma unroll
      for (int f=0; f<NF; f++)
        bb[d][f] = *(const long*)&wp[((size_t)dd*4*NW + (size_t)f*16)*8];
    }
  }
}

template<int KSTEPS, int NW, int NF>
DEV void gphase(const u8* __restrict__ Wt,
                const u8* __restrict__ zin,
                int nbase, int r16, int g, int rot, f32x4 (&acc)[NF],
                long (&bb)[6][NF]){
  #pragma unroll
  for (int f=0;f<NF;f++) acc[f] = (f32x4){0.f,0.f,0.f,0.f};
  const u8* wp = Wt + ((size_t)g*NW + nbase + r16)*8;
  #pragma unroll
  for (int s=0; s<KSTEPS; s++){
    if (s+5 < KSTEPS){
      int ss5 = (s + 5 + rot) & (KSTEPS-1);
      const u8* wn = wp + (size_t)ss5*4*NW*8;
      #pragma unroll
      for (int f=0; f<NF; f++)
        bb[(s+5)%6][f] = *(const long*)&wn[(size_t)f*128];
    }
    int ss = (s + rot) & (KSTEPS-1);
    long a = *(const long*)&zin[(ss*4+g)*128 + r16*8];
    #pragma unroll
    for (int f=0; f<NF; f++)
      acc[f] = __builtin_amdgcn_mfma_f32_16x16x32_fp8_fp8(a, bb[s%6][f], acc[f],0,0,0);
  }
}

__global__ __launch_bounds__(1024,4) void layer_k(LayerP p){
  __shared__ __align__(16) u8 sZ[2][8192];   // 16 rows x 512 cols, k8-tiled, fp8
  __shared__ float4 psum[16][32];    // h rows (prologue row-scan)
  __shared__ float4 psumC[16][32];   // chunk partial sums
  const int tid = threadIdx.x;
  const int w = tid >> 6, lane = tid & 63;   // w: 0..15
  const int r16 = lane & 15, g = lane >> 4;
  const int rb = blockIdx.x;                 // rows rb*16 .. rb*16+15
  const int nb = w*32;                       // 32-col slice per wave
  const int rot = (rb >> 3) & 15;

  long bb[6][2];

  // earliest: fwd1 weight prefetch + v/h register prefetch + epilogue scalars.
  wpre<8,512,2>(p.W0T, nb, r16, g, rot, bb);
  float vr[4] = {0.f,0.f,0.f,0.f}, hr[4] = {0.f,0.f,0.f,0.f};
  float im = 0.f, fac = 0.f;
  if (w < 8){
    const int col = w*16 + r16;
    #pragma unroll
    for (int j=0;j<4;j++){
      size_t o = ((size_t)rb*16 + g*4 + j)*128 + col;
      hr[j] = p.h[o];
      vr[j] = p.first ? 0.f : p.v[o];
    }
    im  = INV6/(softplus_f(p.rawm[0]) + 0.001f);   // fold fp8 decode into im
    fac = 1.0f/(1.0f + softplus_f(p.rawg[0]));
  }

  // ---- prologue (waves 0..7): cumulative mean -> sZ[0] = [fp8(SZC*xi)|fp8(SZC*h)] ----
  if (tid < 512){
    const int row = tid >> 5;                // 0..15
    const int lane32 = tid & 31;
    const int b = rb >> 5, c = rb & 31;
    const float4* S4 = (const float4*)(p.Sprev + (size_t)b*32*128) + lane32;
    float4 part = {0.f,0.f,0.f,0.f};
    if (row < c){
      float4 t = S4[(size_t)row*32];
      part.x+=t.x; part.y+=t.y; part.z+=t.z; part.w+=t.w;
    }
    if (row+16 < c){
      float4 t = S4[(size_t)(row+16)*32];
      part.x+=t.x; part.y+=t.y; part.z+=t.z; part.w+=t.w;
    }
    float4 myrow = ((const float4*)(p.h + (size_t)rb*16*128))[(size_t)row*32 + lane32];
    psum[row][lane32]  = myrow;
    psumC[row][lane32] = part;
    __syncthreads();
    float4 pfx = {0.f,0.f,0.f,0.f};
    #pragma unroll
    for (int r=0;r<16;r++){
      float4 t = psumC[r][lane32];
      pfx.x+=t.x; pfx.y+=t.y; pfx.z+=t.z; pfx.w+=t.w;
    }
    #pragma unroll
    for (int rr=0; rr<15; rr++){
      float4 t = psum[rr][lane32];
      float sel = rr < row ? 1.0f : 0.0f;
      pfx.x += sel*t.x; pfx.y += sel*t.y; pfx.z += sel*t.z; pfx.w += sel*t.w;
    }
    pfx.x+=myrow.x; pfx.y+=myrow.y; pfx.z+=myrow.z; pfx.w+=myrow.w;
    float inv32 = SZC/(float)(c*16 + row + 1);
    const int d0 = lane32*4;
    unsigned ux = pk4_fp8(pfx.x*inv32, pfx.y*inv32, pfx.z*inv32, pfx.w*inv32);
    unsigned uh = pk4_fp8(myrow.x*SZC, myrow.y*SZC, myrow.z*SZC, myrow.w*SZC);
    *(unsigned*)&sZ[0][(d0>>3)*128      + row*8 + (d0&7)] = ux;   // xi cols 0..127
    *(unsigned*)&sZ[0][(16+(d0>>3))*128 + row*8 + (d0&7)] = uh;   // h  cols 128..255
  } else {
    __syncthreads();                         // match prologue's barrier
  }
  __syncthreads();

  f32x4 acc[2];
  unsigned g1p[2][2], g2p[2][2];

  // fwd1: Zc @ W0 (K=256) -> z1 (sZ[1]), g1 packed
  gphase<8,512,2>(p.W0T, sZ[0], nb, r16, g, rot, acc, bb);
  wpre<16,512,2>(p.W1T, nb, r16, g, rot, bb);
  #pragma unroll
  for (int f=0; f<2; f++){
    int n = nb + f*16 + r16;
    float bias = p.b0[n];
    #pragma unroll
    for (int jp=0; jp<2; jp++){
      float z0, dz0, z1v, dz1;
      gelu_pair(acc[f][2*jp]*INV1   + bias, z0,  dz0);
      gelu_pair(acc[f][2*jp+1]*INV1 + bias, z1v, dz1);
      g1p[f][jp] = pack2bf(dz0, dz1);
      sZ[1][(n>>3)*128 + (g*4+2*jp)*8   + (n&7)] = f2fp8(z0*SZ1);
      sZ[1][(n>>3)*128 + (g*4+2*jp+1)*8 + (n&7)] = f2fp8(z1v*SZ1);
    }
  }
  __syncthreads();

  // fwd2: z1 @ W1 -> z2 (sZ[0]), g2 packed
  gphase<16,512,2>(p.W1T, sZ[1], nb, r16, g, rot, acc, bb);
  wpre<16,512,2>(p.W2T, nb, r16, g, rot, bb);
  #pragma unroll
  for (int f=0; f<2; f++){
    int n = nb + f*16 + r16;
    float bias = p.b1[n];
    #pragma unroll
    for (int jp=0; jp<2; jp++){
      float z0, dz0, z1v, dz1;
      gelu_pair(acc[f][2*jp]*INV2   + bias, z0,  dz0);
      gelu_pair(acc[f][2*jp+1]*INV2 + bias, z1v, dz1);
      g2p[f][jp] = pack2bf(dz0, dz1);
      sZ[0][(n>>3)*128 + (g*4+2*jp)*8   + (n&7)] = f2fp8(z0*SZ2);
      sZ[0][(n>>3)*128 + (g*4+2*jp+1)*8 + (n&7)] = f2fp8(z1v*SZ2);
    }
  }
  __syncthreads();

  // fwd3: z2 @ W2 -> gp3 = W3*gelu'(pre3) (sZ[1])
  gphase<16,512,2>(p.W2T, sZ[0], nb, r16, g, rot, acc, bb);
  wpre<16,512,2>(p.W2b, nb, r16, g, rot, bb);
  #pragma unroll
  for (int f=0; f<2; f++){
    int n = nb + f*16 + r16;
    float bias = p.b2[n];
    float w3s = p.W3[n]*SG3;
    #pragma unroll
    for (int j=0;j<4;j++){
      float xx = acc[f][j]*INV3 + bias;
      sZ[1][(n>>3)*128 + (g*4+j)*8 + (n&7)] = f2fp8(w3s*dgelu_f(xx));
    }
  }
  __syncthreads();

  // bwd2: gp2 = (gp3 @ W2b) * g2 (sZ[0])
  gphase<16,512,2>(p.W2b, sZ[1], nb, r16, g, rot, acc, bb);
  wpre<16,512,2>(p.W1b, nb, r16, g, rot, bb);
  #pragma unroll
  for (int f=0; f<2; f++){
    int n = nb + f*16 + r16;
    #pragma unroll
    for (int jp=0; jp<2; jp++){
      float gv0 = unp_lo(g2p[f][jp]), gv1 = unp_hi(g2p[f][jp]);
      sZ[0][(n>>3)*128 + (g*4+2*jp)*8   + (n&7)] = f2fp8(acc[f][2*jp]*gv0*EN4);
      sZ[0][(n>>3)*128 + (g*4+2*jp+1)*8 + (n&7)] = f2fp8(acc[f][2*jp+1]*gv1*EN4);
    }
  }
  __syncthreads();

  // bwd1: gp1 = (gp2 @ W1b) * g1 (sZ[1])
  gphase<16,512,2>(p.W1b, sZ[0], nb, r16, g, rot, acc, bb);
  long bbF[6][1];
  if (w < 8) wpre<16,128,1>(p.W0h, w*16, r16, g, rot, bbF);
  #pragma unroll
  for (int f=0; f<2; f++){
    int n = nb + f*16 + r16;
    #pragma unroll
    for (int jp=0; jp<2; jp++){
      float gv0 = unp_lo(g1p[f][jp]), gv1 = unp_hi(g1p[f][jp]);
      sZ[1][(n>>3)*128 + (g*4+2*jp)*8   + (n&7)] = f2fp8(acc[f][2*jp]*gv0*EN5);
      sZ[1][(n>>3)*128 + (g*4+2*jp+1)*8 + (n&7)] = f2fp8(acc[f][2*jp+1]*gv1*EN5);
    }
  }
  __syncthreads();

  // bwdF (waves 0..7): gradh = gp1 @ W0h (N=128); v,h update from the
  // register-prefetched vr/hr; dead stores skipped via first/last.
  if (w < 8){
    f32x4 accF[1];
    gphase<16,128,1>(p.W0h, sZ[1], w*16, r16, g, rot, accF, bbF);
    int col = w*16 + r16;
    float hs = 0.f;
    #pragma unroll
    for (int j=0;j<4;j++){
      int row = g*4 + j;
      size_t o = ((size_t)rb*16 + row)*128 + col;
      float nv = (vr[j] - accF[0][j]*im)*fac;   // f = -gradh
      float nh = hr[j] + nv;
      if (!p.last){ p.v[o] = nv; p.h[o] = nh; }
      else        { p.hbf[o] = __float2bfloat16(nh); }
      hs += nh;
    }
    if (!p.last){
      hs += __shfl_xor(hs, 16);
      hs += __shfl_xor(hs, 32);
      if (g==0) p.Snext[(size_t)rb*128 + col] = hs;
    }
  }
}

// ---------------- logits: out = hbf(4096x128) @ Ebf(50257x128)^T, fp32 ----------------
// BM=256 x BN=64 (was 128x128): same per-wave 64x64 geometry, same grid count
// (16 x 786 = 12576), but mt bands 32 -> 16 so the L3-resident Ebf stream
// halves (412 -> 206 MB); A-reads double but are L2-hits (hbf band 128KB).
// Cached stores + n-major sweep within each XCD slice (1572 = 2 mt x 786 nt).
__global__ __launch_bounds__(256,4) void logits_k(const __hip_bfloat16* __restrict__ A,
                                                  const __hip_bfloat16* __restrict__ Bt,
                                                  float* __restrict__ out){
  constexpr int V = 50257;
  __shared__ __align__(16) __hip_bfloat16 sA[256*64];   // 32KB
  __shared__ __align__(16) __hip_bfloat16 sB[64*64];    // 8KB  -> 40KB total, 4 blocks/CU
  const int tid = threadIdx.x, lane = tid & 63, wave = tid >> 6;
  const int wg = ((blockIdx.x & 7) * 1572) + (blockIdx.x >> 3);
  const int mt = wg / 786, nt = wg % 786;   // n-major within XCD slice
  const int m0 = mt*256, n0 = nt*64;
  const int wm = wave*64;                   // 4 waves stacked in M
  const int r16 = lane & 15, g = lane >> 4;
  const int srow = tid >> 3;
  const int scol = ((tid & 7) ^ (srow & 7)) * 8;
  const int sx = (r16 & 7) * 8;
  f32x4 zero = {0.f,0.f,0.f,0.f};
  f32x4 acc[4][4];   // [tb (n-subtile)][ta (m-subtile)]
  #pragma unroll
  for (int i=0;i<4;i++){ acc[i][0]=zero; acc[i][1]=zero; acc[i][2]=zero; acc[i][3]=zero; }

  auto stageA = [&](int ks){
    #pragma unroll
    for (int i=0;i<8;i++)
      gload_lds16(A + (size_t)(m0 + i*32 + srow)*128 + ks*64 + scol,
                  &sA[i*2048 + wave*512]);
  };
  auto stageB = [&](int ks){
    #pragma unroll
    for (int i=0;i<2;i++){
      int r = n0 + i*32 + srow; if (r > V-1) r = V-1;
      gload_lds16(Bt + (size_t)r*128 + ks*64 + scol,
                  &sB[i*2048 + wave*512]);
    }
  };
  stageA(0); stageB(0);
  __syncthreads();
  #pragma unroll
  for (int ks=0; ks<2; ks++){
    #pragma unroll
    for (int kk=0; kk<2; kk++){
      const int ko = kk*32 + g*8;
      short8 a[4], b[4];
      #pragma unroll
      for (int ti=0; ti<4; ti++) a[ti] = *(const short8*)&sA[(wm + ti*16 + r16)*64 + (ko ^ sx)];
      #pragma unroll
      for (int tj=0; tj<4; tj++) b[tj] = *(const short8*)&sB[(tj*16 + r16)*64 + (ko ^ sx)];
      #pragma unroll
      for (int tb=0; tb<4; tb++)
        #pragma unroll
        for (int ta=0; ta<4; ta++)
          acc[tb][ta] = __builtin_amdgcn_mfma_f32_16x16x32_bf16(b[tb],a[ta],acc[tb][ta],0,0,0);
    }
    if (ks==0){
      __syncthreads();          // all reads of step-0 tile done
      stageA(1); stageB(1);
      __syncthreads();          // step-1 tile landed
    }
  }
  #pragma unroll
  for (int tb=0; tb<4; tb++){
    #pragma unroll
    for (int ta=0; ta<4; ta++){
      int row = m0 + wm + ta*16 + r16;
      int n   = n0 + tb*16 + g*4;
      f32x4 c = acc[tb][ta];
      float* po = out + (size_t)row*V + n;
      if (n + 3 < V){
        store_f4_a4(po, c);
      } else {
        #pragma unroll
        for (int j=0;j<4;j++) if (n+j < V) po[j] = c[j];
      }
    }
  }
}

extern "C" void kernel_launch(void* const* d_in, const int* in_sizes, int n_in,
                              void* d_out, int out_size, void* d_ws, size_t ws_size,
                              hipStream_t stream){
  const int*   x    = (const int*)  d_in[0];
  const float* E    = (const float*)d_in[1];
  const float* P    = (const float*)d_in[2];
  const float* W0   = (const float*)d_in[3];
  const float* b0   = (const float*)d_in[4];
  const float* W1   = (const float*)d_in[5];
  const float* b1   = (const float*)d_in[6];
  const float* W2   = (const float*)d_in[7];
  const float* b2   = (const float*)d_in[8];
  const float* W3   = (const float*)d_in[9];
  const float* rawm = (const float*)d_in[11];
  const float* rawg = (const float*)d_in[12];

  constexpr int B=8, T=512, D=128, V=50257, L=8;
  const int M = B*T;                       // 4096

  char* w = (char*)d_ws;
  auto alloc = [&](size_t bytes)->char*{ char* r = w; w += (bytes + 255) & ~(size_t)255; return r; };
  float* h            = (float*)alloc((size_t)M*D*4);
  float* v            = (float*)alloc((size_t)M*D*4);
  __hip_bfloat16* hbf = (__hip_bfloat16*)alloc((size_t)M*D*2);
  float* S0           = (float*)alloc((size_t)B*32*128*4);
  float* S1           = (float*)alloc((size_t)B*32*128*4);
  u8* W0T             = (u8*)alloc((size_t)131072);
  u8* W1T             = (u8*)alloc((size_t)262144);
  u8* W2T             = (u8*)alloc((size_t)262144);
  u8* W2b             = (u8*)alloc((size_t)262144);
  u8* W1b             = (u8*)alloc((size_t)262144);
  u8* W0h             = (u8*)alloc((size_t)65536);
  __hip_bfloat16* Ebf = (__hip_bfloat16*)alloc((size_t)V*D*2);

  convw_k  <<<4864, 256, 0, stream>>>(W0, W1, W2, W0T, W1T, W2T, W2b, W1b, W0h);
  conv_c4_k<<<(V*D/4+255)/256, 256, 0, stream>>>(E, Ebf, V*D/4);
  embed_k<<<M/16, 512, 0, stream>>>(x, E, P, h, S0);

  LayerP lp{};
  lp.W0T=W0T; lp.W1T=W1T; lp.W2T=W2T; lp.W2b=W2b; lp.W1b=W1b; lp.W0h=W0h;
  lp.b0=b0; lp.b1=b1; lp.b2=b2; lp.W3=W3;
  lp.v=v; lp.h=h; lp.hbf=hbf; lp.rawm=rawm; lp.rawg=rawg;

  for (int l=0; l<L; l++){
    lp.Sprev = (l&1) ? S1 : S0;
    lp.Snext = (l&1) ? S0 : S1;
    lp.first = (l==0) ? 1 : 0;
    lp.last  = (l==L-1) ? 1 : 0;
    layer_k<<<M/16, 1024, 0, stream>>>(lp);
  }
  logits_k<<<12576, 256, 0, stream>>>(hbf, Ebf, (float*)d_out);
}

// Round 12
// 507.290 us; speedup vs baseline: 1.0666x; 1.0666x over previous
//
#include <hip/hip_runtime.h>
#include <hip/hip_bf16.h>

typedef __attribute__((ext_vector_type(8))) short short8;
typedef __attribute__((ext_vector_type(4))) float f32x4;
typedef unsigned char u8;

#define DEV static __device__ __forceinline__

// branchless A&S erf gelu; one __expf(-x^2/2) serves erf tail + pdf term
DEV void gelu_pair(float x, float& z, float& dz){
  float ax = fabsf(x)*0.70710678118654752f;
  float e  = __expf(-ax*ax);
  float t  = __fdividef(1.0f, 1.0f + 0.3275911f*ax);
  float poly = t*(0.254829592f + t*(-0.284496736f + t*(1.421413741f +
               t*(-1.453152027f + t*1.061405429f))));
  float erfv = 1.0f - poly*e;
  erfv = x < 0.0f ? -erfv : erfv;
  float cdf = 0.5f*(1.0f + erfv);
  z  = x*cdf;
  dz = cdf + x*0.39894228040143268f*e;
}
DEV float dgelu_f(float x){ float zz, dz; gelu_pair(x, zz, dz); return dz; }
DEV float softplus_f(float x){ return log1pf(expf(x)); }
DEV void store_f4_a4(float* p, f32x4 v){ __builtin_memcpy(p, &v, 16); }

DEV void gload_lds16(const __hip_bfloat16* g, __hip_bfloat16* l){
  __builtin_amdgcn_global_load_lds((const __attribute__((address_space(1))) void*)g,
                                   (__attribute__((address_space(3))) void*)l, 16, 0, 0);
}

// fp8 e4m3 (gfx950 OCP) encode via HW cvt — same HW format the fp8 MFMA consumes
DEV u8 f2fp8(float f){
  int r = __builtin_amdgcn_cvt_pk_fp8_f32(f, f, 0, false);
  return (u8)(r & 0xff);
}
DEV unsigned pk4_fp8(float a, float b, float c, float d){
  int r = __builtin_amdgcn_cvt_pk_fp8_f32(a, b, 0, false);
  r = __builtin_amdgcn_cvt_pk_fp8_f32(c, d, r, true);
  return (unsigned)r;
}

DEV unsigned pack2bf(float a, float b){
  __hip_bfloat16 ba = __float2bfloat16(a), bb = __float2bfloat16(b);
  unsigned short ua, ub;
  __builtin_memcpy(&ua, &ba, 2); __builtin_memcpy(&ub, &bb, 2);
  return (unsigned)ua | ((unsigned)ub << 16);
}
DEV float unp_lo(unsigned u){ union{unsigned x; float f;} c; c.x = u << 16; return c.f; }
DEV float unp_hi(unsigned u){ union{unsigned x; float f;} c; c.x = u & 0xffff0000u; return c.f; }

// stream scales (exact powers of 2): encode value*S into fp8, decode by folding
// 1/(Sa*Sw) into the epilogue.
#define SW    32.0f
#define SZC   32.0f
#define SZ1   256.0f
#define SZ2   1024.0f
#define SG3   256.0f
#define INV1  (1.0f/1024.0f)
#define INV2  (1.0f/8192.0f)
#define INV3  (1.0f/32768.0f)
#define EN4   0.125f
#define EN5   0.125f
#define INV6  (1.0f/131072.0f)

// ---------------- embed: h = E[x] + P, S = 16-row chunk sums (v implicit 0 at layer 0) ----------------
__global__ __launch_bounds__(512) void embed_k(const int* __restrict__ x,
                        const float* __restrict__ E, const float* __restrict__ P,
                        float* __restrict__ h, float* __restrict__ S){
  int bid = blockIdx.x;
  int row = threadIdx.x >> 5;
  int q   = threadIdx.x & 31;
  int tok = bid*16 + row;
  int t   = tok & 511;
  int id  = x[tok];
  float4 e4 = ((const float4*)E)[(size_t)id*32 + q];
  float4 p4 = ((const float4*)P)[(size_t)t*32 + q];
  float4 val; val.x=e4.x+p4.x; val.y=e4.y+p4.y; val.z=e4.z+p4.z; val.w=e4.w+p4.w;
  ((float4*)h)[(size_t)tok*32 + q] = val;
  __shared__ float4 ps[16][32];
  ps[row][q] = val;
  __syncthreads();
  if (row==0){
    float4 s = ps[0][q];
    #pragma unroll
    for (int r=1;r<16;r++){
      float4 t4 = ps[r][q];
      s.x+=t4.x; s.y+=t4.y; s.z+=t4.z; s.w+=t4.w;
    }
    ((float4*)S)[(size_t)bid*32 + q] = s;
  }
}

// ---------------- weight pre-tiling into MFMA B-fragment order, fp8 e4m3 ----------------
// layout: Wt[(k>>3)*N*8 + n*8 + (k&7)] = fp8(SW * W_logical[n][k])
__global__ void convw_k(const float* __restrict__ W0, const float* __restrict__ W1,
                        const float* __restrict__ W2,
                        u8* __restrict__ W0T, u8* __restrict__ W1T,
                        u8* __restrict__ W2T, u8* __restrict__ W2b,
                        u8* __restrict__ W1b, u8* __restrict__ W0h){
  int i = blockIdx.x*256 + threadIdx.x;
  if (i < 131072){                     // W0T: B[n][k]=W0[k][n], K=256
    int e=i&7, n=(i>>3)&511, kk=i>>12; int k=(kk>>2)*32+(kk&3)*8+e;
    W0T[i]=f2fp8(SW*W0[(size_t)k*512+n]);
  } else if (i < 393216){              // W1T
    int j=i-131072; int e=j&7, n=(j>>3)&511, kk=j>>12; int k=(kk>>2)*32+(kk&3)*8+e;
    W1T[j]=f2fp8(SW*W1[(size_t)k*512+n]);
  } else if (i < 655360){              // W2T
    int j=i-393216; int e=j&7, n=(j>>3)&511, kk=j>>12; int k=(kk>>2)*32+(kk&3)*8+e;
    W2T[j]=f2fp8(SW*W2[(size_t)k*512+n]);
  } else if (i < 917504){              // W2b: B[n][k]=W2[n][k]
    int j=i-655360; int e=j&7, n=(j>>3)&511, kk=j>>12; int k=(kk>>2)*32+(kk&3)*8+e;
    W2b[j]=f2fp8(SW*W2[(size_t)n*512+k]);
  } else if (i < 1179648){             // W1b
    int j=i-917504; int e=j&7, n=(j>>3)&511, kk=j>>12; int k=(kk>>2)*32+(kk&3)*8+e;
    W1b[j]=f2fp8(SW*W1[(size_t)n*512+k]);
  } else if (i < 1245184){             // W0h: B[d][k]=W0[128+d][k], N=128
    int j=i-1179648; int e=j&7, n=(j>>3)&127, kk=j>>10; int k=(kk>>2)*32+(kk&3)*8+e;
    W0h[j]=f2fp8(SW*W0[(size_t)(128+n)*512+k]);
  }
}
__global__ void conv_c4_k(const float* __restrict__ W, __hip_bfloat16* __restrict__ Wb, int n4){
  int i = blockIdx.x*256 + threadIdx.x;
  if (i < n4){
    float4 f = ((const float4*)W)[i];
    Wb[4*i+0]=__float2bfloat16(f.x);
    Wb[4*i+1]=__float2bfloat16(f.y);
    Wb[4*i+2]=__float2bfloat16(f.z);
    Wb[4*i+3]=__float2bfloat16(f.w);
  }
}

// ---------------- fused layer kernel, M-tile 16, 1024 threads (4 waves/SIMD) ----------------
struct LayerP {
  const u8 *W0T,*W1T,*W2T,*W2b,*W1b,*W0h;
  const float *b0,*b1,*b2,*W3;
  float *v, *h; __hip_bfloat16* hbf;
  const float* Sprev; float* Snext;
  const float *rawm,*rawg;
  int first, last;
};

// depth-5 / mod-6 ring prefetch; K-rotation de-phases the 32 CUs sharing an XCD.
template<int KSTEPS, int NW, int NF>
DEV void wpre(const u8* __restrict__ Wt, int nbase, int r16, int g, int rot,
              long (&bb)[6][NF]){
  const u8* wp = Wt + ((size_t)g*NW + nbase + r16)*8;
  #pragma unroll
  for (int d=0; d<5; d++){
    if (d < KSTEPS){
      int dd = (d + rot) & (KSTEPS-1);
      #pragma unroll
      for (int f=0; f<NF; f++)
        bb[d][f] = *(const long*)&wp[((size_t)dd*4*NW + (size_t)f*16)*8];
    }
  }
}

template<int KSTEPS, int NW, int NF>
DEV void gphase(const u8* __restrict__ Wt,
                const u8* __restrict__ zin,
                int nbase, int r16, int g, int rot, f32x4 (&acc)[NF],
                long (&bb)[6][NF]){
  #pragma unroll
  for (int f=0;f<NF;f++) acc[f] = (f32x4){0.f,0.f,0.f,0.f};
  const u8* wp = Wt + ((size_t)g*NW + nbase + r16)*8;
  #pragma unroll
  for (int s=0; s<KSTEPS; s++){
    if (s+5 < KSTEPS){
      int ss5 = (s + 5 + rot) & (KSTEPS-1);
      const u8* wn = wp + (size_t)ss5*4*NW*8;
      #pragma unroll
      for (int f=0; f<NF; f++)
        bb[(s+5)%6][f] = *(const long*)&wn[(size_t)f*128];
    }
    int ss = (s + rot) & (KSTEPS-1);
    long a = *(const long*)&zin[(ss*4+g)*128 + r16*8];
    #pragma unroll
    for (int f=0; f<NF; f++)
      acc[f] = __builtin_amdgcn_mfma_f32_16x16x32_fp8_fp8(a, bb[s%6][f], acc[f],0,0,0);
  }
}

__global__ __launch_bounds__(1024,4) void layer_k(LayerP p){
  __shared__ __align__(16) u8 sZ[2][8192];   // 16 rows x 512 cols, k8-tiled, fp8
  __shared__ float4 psum[16][32];    // h rows — persists to bwdF (proven in R5)
  __shared__ float4 psumC[16][32];   // chunk partial sums
  const int tid = threadIdx.x;
  const int w = tid >> 6, lane = tid & 63;   // w: 0..15
  const int r16 = lane & 15, g = lane >> 4;
  const int rb = blockIdx.x;                 // rows rb*16 .. rb*16+15
  const int nb = w*32;                       // 32-col slice per wave
  const int rot = (rb >> 3) & 15;

  long bb[6][2];

  // earliest: fwd1 weight prefetch + v register prefetch + epilogue scalars.
  // h comes from psum (LDS) in bwdF — no global h re-read.
  wpre<8,512,2>(p.W0T, nb, r16, g, rot, bb);
  float vr[4] = {0.f,0.f,0.f,0.f};
  float im = 0.f, fac = 0.f;
  if (w < 8){
    const int col = w*16 + r16;
    if (!p.first){
      #pragma unroll
      for (int j=0;j<4;j++)
        vr[j] = p.v[((size_t)rb*16 + g*4 + j)*128 + col];
    }
    im  = INV6/(softplus_f(p.rawm[0]) + 0.001f);   // fold fp8 decode into im
    fac = 1.0f/(1.0f + softplus_f(p.rawg[0]));
  }

  // ---- prologue (waves 0..7): cumulative mean -> sZ[0] = [fp8(SZC*xi)|fp8(SZC*h)] ----
  if (tid < 512){
    const int row = tid >> 5;                // 0..15
    const int lane32 = tid & 31;
    const int b = rb >> 5, c = rb & 31;
    const float4* S4 = (const float4*)(p.Sprev + (size_t)b*32*128) + lane32;
    float4 part = {0.f,0.f,0.f,0.f};
    if (row < c){
      float4 t = S4[(size_t)row*32];
      part.x+=t.x; part.y+=t.y; part.z+=t.z; part.w+=t.w;
    }
    if (row+16 < c){
      float4 t = S4[(size_t)(row+16)*32];
      part.x+=t.x; part.y+=t.y; part.z+=t.z; part.w+=t.w;
    }
    float4 myrow = ((const float4*)(p.h + (size_t)rb*16*128))[(size_t)row*32 + lane32];
    psum[row][lane32]  = myrow;
    psumC[row][lane32] = part;
    __syncthreads();
    float4 pfx = {0.f,0.f,0.f,0.f};
    #pragma unroll
    for (int r=0;r<16;r++){
      float4 t = psumC[r][lane32];
      pfx.x+=t.x; pfx.y+=t.y; pfx.z+=t.z; pfx.w+=t.w;
    }
    #pragma unroll
    for (int rr=0; rr<15; rr++){
      float4 t = psum[rr][lane32];
      float sel = rr < row ? 1.0f : 0.0f;
      pfx.x += sel*t.x; pfx.y += sel*t.y; pfx.z += sel*t.z; pfx.w += sel*t.w;
    }
    pfx.x+=myrow.x; pfx.y+=myrow.y; pfx.z+=myrow.z; pfx.w+=myrow.w;
    float inv32 = SZC/(float)(c*16 + row + 1);
    const int d0 = lane32*4;
    unsigned ux = pk4_fp8(pfx.x*inv32, pfx.y*inv32, pfx.z*inv32, pfx.w*inv32);
    unsigned uh = pk4_fp8(myrow.x*SZC, myrow.y*SZC, myrow.z*SZC, myrow.w*SZC);
    *(unsigned*)&sZ[0][(d0>>3)*128      + row*8 + (d0&7)] = ux;   // xi cols 0..127
    *(unsigned*)&sZ[0][(16+(d0>>3))*128 + row*8 + (d0&7)] = uh;   // h  cols 128..255
  } else {
    __syncthreads();                         // match prologue's barrier
  }
  __syncthreads();

  f32x4 acc[2];
  unsigned g1p[2][2], g2p[2][2];

  // fwd1: Zc @ W0 (K=256) -> z1 (sZ[1]), g1 packed
  gphase<8,512,2>(p.W0T, sZ[0], nb, r16, g, rot, acc, bb);
  wpre<16,512,2>(p.W1T, nb, r16, g, rot, bb);
  #pragma unroll
  for (int f=0; f<2; f++){
    int n = nb + f*16 + r16;
    float bias = p.b0[n];
    #pragma unroll
    for (int jp=0; jp<2; jp++){
      float z0, dz0, z1v, dz1;
      gelu_pair(acc[f][2*jp]*INV1   + bias, z0,  dz0);
      gelu_pair(acc[f][2*jp+1]*INV1 + bias, z1v, dz1);
      g1p[f][jp] = pack2bf(dz0, dz1);
      sZ[1][(n>>3)*128 + (g*4+2*jp)*8   + (n&7)] = f2fp8(z0*SZ1);
      sZ[1][(n>>3)*128 + (g*4+2*jp+1)*8 + (n&7)] = f2fp8(z1v*SZ1);
    }
  }
  __syncthreads();

  // fwd2: z1 @ W1 -> z2 (sZ[0]), g2 packed
  gphase<16,512,2>(p.W1T, sZ[1], nb, r16, g, rot, acc, bb);
  wpre<16,512,2>(p.W2T, nb, r16, g, rot, bb);
  #pragma unroll
  for (int f=0; f<2; f++){
    int n = nb + f*16 + r16;
    float bias = p.b1[n];
    #pragma unroll
    for (int jp=0; jp<2; jp++){
      float z0, dz0, z1v, dz1;
      gelu_pair(acc[f][2*jp]*INV2   + bias, z0,  dz0);
      gelu_pair(acc[f][2*jp+1]*INV2 + bias, z1v, dz1);
      g2p[f][jp] = pack2bf(dz0, dz1);
      sZ[0][(n>>3)*128 + (g*4+2*jp)*8   + (n&7)] = f2fp8(z0*SZ2);
      sZ[0][(n>>3)*128 + (g*4+2*jp+1)*8 + (n&7)] = f2fp8(z1v*SZ2);
    }
  }
  __syncthreads();

  // fwd3: z2 @ W2 -> gp3 = W3*gelu'(pre3) (sZ[1])
  gphase<16,512,2>(p.W2T, sZ[0], nb, r16, g, rot, acc, bb);
  wpre<16,512,2>(p.W2b, nb, r16, g, rot, bb);
  #pragma unroll
  for (int f=0; f<2; f++){
    int n = nb + f*16 + r16;
    float bias = p.b2[n];
    float w3s = p.W3[n]*SG3;
    #pragma unroll
    for (int j=0;j<4;j++){
      float xx = acc[f][j]*INV3 + bias;
      sZ[1][(n>>3)*128 + (g*4+j)*8 + (n&7)] = f2fp8(w3s*dgelu_f(xx));
    }
  }
  __syncthreads();

  // bwd2: gp2 = (gp3 @ W2b) * g2 (sZ[0])
  gphase<16,512,2>(p.W2b, sZ[1], nb, r16, g, rot, acc, bb);
  wpre<16,512,2>(p.W1b, nb, r16, g, rot, bb);
  #pragma unroll
  for (int f=0; f<2; f++){
    int n = nb + f*16 + r16;
    #pragma unroll
    for (int jp=0; jp<2; jp++){
      float gv0 = unp_lo(g2p[f][jp]), gv1 = unp_hi(g2p[f][jp]);
      sZ[0][(n>>3)*128 + (g*4+2*jp)*8   + (n&7)] = f2fp8(acc[f][2*jp]*gv0*EN4);
      sZ[0][(n>>3)*128 + (g*4+2*jp+1)*8 + (n&7)] = f2fp8(acc[f][2*jp+1]*gv1*EN4);
    }
  }
  __syncthreads();

  // bwd1: gp1 = (gp2 @ W1b) * g1 (sZ[1])
  gphase<16,512,2>(p.W1b, sZ[0], nb, r16, g, rot, acc, bb);
  long bbF[6][1];
  if (w < 8) wpre<16,128,1>(p.W0h, w*16, r16, g, rot, bbF);
  #pragma unroll
  for (int f=0; f<2; f++){
    int n = nb + f*16 + r16;
    #pragma unroll
    for (int jp=0; jp<2; jp++){
      float gv0 = unp_lo(g1p[f][jp]), gv1 = unp_hi(g1p[f][jp]);
      sZ[1][(n>>3)*128 + (g*4+2*jp)*8   + (n&7)] = f2fp8(acc[f][2*jp]*gv0*EN5);
      sZ[1][(n>>3)*128 + (g*4+2*jp+1)*8 + (n&7)] = f2fp8(acc[f][2*jp+1]*gv1*EN5);
    }
  }
  __syncthreads();

  // bwdF (waves 0..7): gradh = gp1 @ W0h (N=128); v from registers, h from psum
  // (LDS, staged in prologue — indexing proven in R5); dead stores via first/last.
  if (w < 8){
    f32x4 accF[1];
    gphase<16,128,1>(p.W0h, sZ[1], w*16, r16, g, rot, accF, bbF);
    int col = w*16 + r16;
    float hs = 0.f;
    #pragma unroll
    for (int j=0;j<4;j++){
      int row = g*4 + j;
      size_t o = ((size_t)rb*16 + row)*128 + col;
      float hold = ((const float*)psum)[row*128 + col];
      float nv = (vr[j] - accF[0][j]*im)*fac;   // f = -gradh
      float nh = hold + nv;
      if (!p.last){ p.v[o] = nv; p.h[o] = nh; }
      else        { p.hbf[o] = __float2bfloat16(nh); }
      hs += nh;
    }
    if (!p.last){
      hs += __shfl_xor(hs, 16);
      hs += __shfl_xor(hs, 32);
      if (g==0) p.Snext[(size_t)rb*128 + col] = hs;
    }
  }
}

// ---------------- logits: out = hbf(4096x128) @ Ebf(50257x128)^T, fp32 ----------------
// R10 config (best): 128x128 tile, cached stores, n-MAJOR tile order within each
// XCD slice (1572 = 4 mt x 393 nt): co-resident blocks sweep consecutive nt
// stripes of the same 128 rows -> fill-like HBM write page locality.
__global__ __launch_bounds__(256,4) void logits_k(const __hip_bfloat16* __restrict__ A,
                                                  const __hip_bfloat16* __restrict__ Bt,
                                                  float* __restrict__ out){
  constexpr int V = 50257;
  __shared__ __align__(16) __hip_bfloat16 sA[128*64];
  __shared__ __align__(16) __hip_bfloat16 sB[128*64];
  const int tid = threadIdx.x, lane = tid & 63, wave = tid >> 6;
  const int wg = ((blockIdx.x & 7) * 1572) + (blockIdx.x >> 3);
  const int mt = wg / 393, nt = wg % 393;   // n-major within XCD slice
  const int m0 = mt*128, n0 = nt*128;
  const int wm = (wave>>1)*64, wn = (wave&1)*64;
  const int r16 = lane & 15, g = lane >> 4;
  const int srow = tid >> 3;
  const int scol = ((tid & 7) ^ (srow & 7)) * 8;
  const int sx = (r16 & 7) * 8;
  f32x4 zero = {0.f,0.f,0.f,0.f};
  f32x4 acc[4][4];   // [tb (n-subtile)][ta (m-subtile)]
  #pragma unroll
  for (int i=0;i<4;i++){ acc[i][0]=zero; acc[i][1]=zero; acc[i][2]=zero; acc[i][3]=zero; }

  auto stageA = [&](int ks){
    #pragma unroll
    for (int i=0;i<4;i++)
      gload_lds16(A + (size_t)(m0 + i*32 + srow)*128 + ks*64 + scol,
                  &sA[i*2048 + wave*512]);
  };
  auto stageB = [&](int ks){
    #pragma unroll
    for (int i=0;i<4;i++){
      int r = n0 + i*32 + srow; if (r > V-1) r = V-1;
      gload_lds16(Bt + (size_t)r*128 + ks*64 + scol,
                  &sB[i*2048 + wave*512]);
    }
  };
  stageA(0); stageB(0);
  __syncthreads();
  #pragma unroll
  for (int ks=0; ks<2; ks++){
    #pragma unroll
    for (int kk=0; kk<2; kk++){
      const int ko = kk*32 + g*8;
      short8 a[4], b[4];
      #pragma unroll
      for (int ti=0; ti<4; ti++) a[ti] = *(const short8*)&sA[(wm + ti*16 + r16)*64 + (ko ^ sx)];
      #pragma unroll
      for (int tj=0; tj<4; tj++) b[tj] = *(const short8*)&sB[(wn + tj*16 + r16)*64 + (ko ^ sx)];
      #pragma unroll
      for (int tb=0; tb<4; tb++)
        #pragma unroll
        for (int ta=0; ta<4; ta++)
          acc[tb][ta] = __builtin_amdgcn_mfma_f32_16x16x32_bf16(b[tb],a[ta],acc[tb][ta],0,0,0);
    }
    if (ks==0){
      __syncthreads();          // all reads of step-0 tile done
      stageA(1); stageB(1);
      __syncthreads();          // step-1 tile landed
    }
  }
  #pragma unroll
  for (int tb=0; tb<4; tb++){
    #pragma unroll
    for (int ta=0; ta<4; ta++){
      int row = m0 + wm + ta*16 + r16;
      int n   = n0 + wn + tb*16 + g*4;
      f32x4 c = acc[tb][ta];
      float* po = out + (size_t)row*V + n;
      if (n + 3 < V){
        store_f4_a4(po, c);
      } else {
        #pragma unroll
        for (int j=0;j<4;j++) if (n+j < V) po[j] = c[j];
      }
    }
  }
}

extern "C" void kernel_launch(void* const* d_in, const int* in_sizes, int n_in,
                              void* d_out, int out_size, void* d_ws, size_t ws_size,
                              hipStream_t stream){
  const int*   x    = (const int*)  d_in[0];
  const float* E    = (const float*)d_in[1];
  const float* P    = (const float*)d_in[2];
  const float* W0   = (const float*)d_in[3];
  const float* b0   = (const float*)d_in[4];
  const float* W1   = (const float*)d_in[5];
  const float* b1   = (const float*)d_in[6];
  const float* W2   = (const float*)d_in[7];
  const float* b2   = (const float*)d_in[8];
  const float* W3   = (const float*)d_in[9];
  const float* rawm = (const float*)d_in[11];
  const float* rawg = (const float*)d_in[12];

  constexpr int B=8, T=512, D=128, V=50257, L=8;
  const int M = B*T;                       // 4096

  char* w = (char*)d_ws;
  auto alloc = [&](size_t bytes)->char*{ char* r = w; w += (bytes + 255) & ~(size_t)255; return r; };
  float* h            = (float*)alloc((size_t)M*D*4);
  float* v            = (float*)alloc((size_t)M*D*4);
  __hip_bfloat16* hbf = (__hip_bfloat16*)alloc((size_t)M*D*2);
  float* S0           = (float*)alloc((size_t)B*32*128*4);
  float* S1           = (float*)alloc((size_t)B*32*128*4);
  u8* W0T             = (u8*)alloc((size_t)131072);
  u8* W1T             = (u8*)alloc((size_t)262144);
  u8* W2T             = (u8*)alloc((size_t)262144);
  u8* W2b             = (u8*)alloc((size_t)262144);
  u8* W1b             = (u8*)alloc((size_t)262144);
  u8* W0h             = (u8*)alloc((size_t)65536);
  __hip_bfloat16* Ebf = (__hip_bfloat16*)alloc((size_t)V*D*2);

  convw_k  <<<4864, 256, 0, stream>>>(W0, W1, W2, W0T, W1T, W2T, W2b, W1b, W0h);
  conv_c4_k<<<(V*D/4+255)/256, 256, 0, stream>>>(E, Ebf, V*D/4);
  embed_k<<<M/16, 512, 0, stream>>>(x, E, P, h, S0);

  LayerP lp{};
  lp.W0T=W0T; lp.W1T=W1T; lp.W2T=W2T; lp.W2b=W2b; lp.W1b=W1b; lp.W0h=W0h;
  lp.b0=b0; lp.b1=b1; lp.b2=b2; lp.W3=W3;
  lp.v=v; lp.h=h; lp.hbf=hbf; lp.rawm=rawm; lp.rawg=rawg;

  for (int l=0; l<L; l++){
    lp.Sprev = (l&1) ? S1 : S0;
    lp.Snext = (l&1) ? S0 : S1;
    lp.first = (l==0) ? 1 : 0;
    lp.last  = (l==L-1) ? 1 : 0;
    layer_k<<<M/16, 1024, 0, stream>>>(lp);
  }
  logits_k<<<12576, 256, 0, stream>>>(hbf, Ebf, (float*)d_out);
}

// Round 14
// 502.326 us; speedup vs baseline: 1.0771x; 1.0099x over previous
//
#include <hip/hip_runtime.h>
#include <hip/hip_bf16.h>

typedef __attribute__((ext_vector_type(8))) short short8;
typedef __attribute__((ext_vector_type(4))) float f32x4;
typedef unsigned char u8;

#define DEV static __device__ __forceinline__

// branchless A&S erf gelu; one __expf(-x^2/2) serves erf tail + pdf term
DEV void gelu_pair(float x, float& z, float& dz){
  float ax = fabsf(x)*0.70710678118654752f;
  float e  = __expf(-ax*ax);
  float t  = __fdividef(1.0f, 1.0f + 0.3275911f*ax);
  float poly = t*(0.254829592f + t*(-0.284496736f + t*(1.421413741f +
               t*(-1.453152027f + t*1.061405429f))));
  float erfv = 1.0f - poly*e;
  erfv = x < 0.0f ? -erfv : erfv;
  float cdf = 0.5f*(1.0f + erfv);
  z  = x*cdf;
  dz = cdf + x*0.39894228040143268f*e;
}
DEV float dgelu_f(float x){ float zz, dz; gelu_pair(x, zz, dz); return dz; }
DEV float softplus_f(float x){ return log1pf(expf(x)); }
DEV void store_f4_a4(float* p, f32x4 v){ __builtin_memcpy(p, &v, 16); }

DEV void gload_lds16(const __hip_bfloat16* g, __hip_bfloat16* l){
  __builtin_amdgcn_global_load_lds((const __attribute__((address_space(1))) void*)g,
                                   (__attribute__((address_space(3))) void*)l, 16, 0, 0);
}

// fp8 e4m3 (gfx950 OCP) encode via HW cvt — same HW format the fp8 MFMA consumes
DEV u8 f2fp8(float f){
  int r = __builtin_amdgcn_cvt_pk_fp8_f32(f, f, 0, false);
  return (u8)(r & 0xff);
}
DEV unsigned pk4_fp8(float a, float b, float c, float d){
  int r = __builtin_amdgcn_cvt_pk_fp8_f32(a, b, 0, false);
  r = __builtin_amdgcn_cvt_pk_fp8_f32(c, d, r, true);
  return (unsigned)r;
}

DEV unsigned pack2bf(float a, float b){
  __hip_bfloat16 ba = __float2bfloat16(a), bb = __float2bfloat16(b);
  unsigned short ua, ub;
  __builtin_memcpy(&ua, &ba, 2); __builtin_memcpy(&ub, &bb, 2);
  return (unsigned)ua | ((unsigned)ub << 16);
}
DEV float unp_lo(unsigned u){ union{unsigned x; float f;} c; c.x = u << 16; return c.f; }
DEV float unp_hi(unsigned u){ union{unsigned x; float f;} c; c.x = u & 0xffff0000u; return c.f; }

// stream scales (exact powers of 2): encode value*S into fp8, decode by folding
// 1/(Sa*Sw) into the epilogue.
#define SW    32.0f
#define SZC   32.0f
#define SZ1   256.0f
#define SZ2   1024.0f
#define SG3   256.0f
#define INV1  (1.0f/1024.0f)
#define INV2  (1.0f/8192.0f)
#define INV3  (1.0f/32768.0f)
#define EN4   0.125f
#define EN5   0.125f
#define INV6  (1.0f/131072.0f)

// ---------------- merged setup: embed (256 blocks) + convw (2432) + conv_c4 (3142) ----------------
// All three are mutually independent (embed: x,E,P -> h,S; convw: W0..W2 -> fp8
// tiles; conv_c4: E -> Ebf). One launch replaces three.
// GRID MUST BE 256 + 2432 + ceil(1608224/512)=3142 = 5830 (R13 bug: 5829 left
// the last 32 float4s of Ebf — vocab row 50256 — uninitialized).
struct SetupP {
  const int* x; const float *E, *P;
  float *h, *S;
  const float *W0, *W1, *W2;
  u8 *W0T,*W1T,*W2T,*W2b,*W1b,*W0h;
  __hip_bfloat16* Ebf;
};

__global__ __launch_bounds__(512) void setup_k(SetupP q){
  const int bid = blockIdx.x, tid = threadIdx.x;
  if (bid < 256){
    // ---- embed: h = E[x] + P, S = 16-row chunk sums ----
    int row = tid >> 5;
    int qq  = tid & 31;
    int tok = bid*16 + row;
    int t   = tok & 511;
    int id  = q.x[tok];
    float4 e4 = ((const float4*)q.E)[(size_t)id*32 + qq];
    float4 p4 = ((const float4*)q.P)[(size_t)t*32 + qq];
    float4 val; val.x=e4.x+p4.x; val.y=e4.y+p4.y; val.z=e4.z+p4.z; val.w=e4.w+p4.w;
    ((float4*)q.h)[(size_t)tok*32 + qq] = val;
    __shared__ float4 ps[16][32];
    ps[row][qq] = val;
    __syncthreads();
    if (row==0){
      float4 s = ps[0][qq];
      #pragma unroll
      for (int r=1;r<16;r++){
        float4 t4 = ps[r][qq];
        s.x+=t4.x; s.y+=t4.y; s.z+=t4.z; s.w+=t4.w;
      }
      ((float4*)q.S)[(size_t)bid*32 + qq] = s;
    }
  } else if (bid < 256 + 2432){
    // ---- convw: weight pre-tiling into MFMA B-fragment order, fp8 e4m3 ----
    // layout: Wt[(k>>3)*N*8 + n*8 + (k&7)] = fp8(SW * W_logical[n][k])
    int i = (bid - 256)*512 + tid;
    if (i < 131072){                     // W0T: B[n][k]=W0[k][n], K=256
      int e=i&7, n=(i>>3)&511, kk=i>>12; int k=(kk>>2)*32+(kk&3)*8+e;
      q.W0T[i]=f2fp8(SW*q.W0[(size_t)k*512+n]);
    } else if (i < 393216){              // W1T
      int j=i-131072; int e=j&7, n=(j>>3)&511, kk=j>>12; int k=(kk>>2)*32+(kk&3)*8+e;
      q.W1T[j]=f2fp8(SW*q.W1[(size_t)k*512+n]);
    } else if (i < 655360){              // W2T
      int j=i-393216; int e=j&7, n=(j>>3)&511, kk=j>>12; int k=(kk>>2)*32+(kk&3)*8+e;
      q.W2T[j]=f2fp8(SW*q.W2[(size_t)k*512+n]);
    } else if (i < 917504){              // W2b: B[n][k]=W2[n][k]
      int j=i-655360; int e=j&7, n=(j>>3)&511, kk=j>>12; int k=(kk>>2)*32+(kk&3)*8+e;
      q.W2b[j]=f2fp8(SW*q.W2[(size_t)n*512+k]);
    } else if (i < 1179648){             // W1b
      int j=i-917504; int e=j&7, n=(j>>3)&511, kk=j>>12; int k=(kk>>2)*32+(kk&3)*8+e;
      q.W1b[j]=f2fp8(SW*q.W1[(size_t)n*512+k]);
    } else if (i < 1245184){             // W0h: B[d][k]=W0[128+d][k], N=128
      int j=i-1179648; int e=j&7, n=(j>>3)&127, kk=j>>10; int k=(kk>>2)*32+(kk&3)*8+e;
      q.W0h[j]=f2fp8(SW*q.W0[(size_t)(128+n)*512+k]);
    }
  } else {
    // ---- conv_c4: E -> bf16 Ebf ----
    constexpr int n4 = 50257*128/4;      // 1608224
    int i = (bid - 2688)*512 + tid;
    if (i < n4){
      float4 f = ((const float4*)q.E)[i];
      q.Ebf[4*i+0]=__float2bfloat16(f.x);
      q.Ebf[4*i+1]=__float2bfloat16(f.y);
      q.Ebf[4*i+2]=__float2bfloat16(f.z);
      q.Ebf[4*i+3]=__float2bfloat16(f.w);
    }
  }
}

// ---------------- fused layer kernel, M-tile 16, 1024 threads (4 waves/SIMD) ----------------
struct LayerP {
  const u8 *W0T,*W1T,*W2T,*W2b,*W1b,*W0h;
  const float *b0,*b1,*b2,*W3;
  float *v, *h; __hip_bfloat16* hbf;
  const float* Sprev; float* Snext;
  const float *rawm,*rawg;
  int first, last;
};

// depth-5 / mod-6 ring prefetch; K-rotation de-phases the 32 CUs sharing an XCD.
template<int KSTEPS, int NW, int NF>
DEV void wpre(const u8* __restrict__ Wt, int nbase, int r16, int g, int rot,
              long (&bb)[6][NF]){
  const u8* wp = Wt + ((size_t)g*NW + nbase + r16)*8;
  #pragma unroll
  for (int d=0; d<5; d++){
    if (d < KSTEPS){
      int dd = (d + rot) & (KSTEPS-1);
      #pragma unroll
      for (int f=0; f<NF; f++)
        bb[d][f] = *(const long*)&wp[((size_t)dd*4*NW + (size_t)f*16)*8];
    }
  }
}

template<int KSTEPS, int NW, int NF>
DEV void gphase(const u8* __restrict__ Wt,
                const u8* __restrict__ zin,
                int nbase, int r16, int g, int rot, f32x4 (&acc)[NF],
                long (&bb)[6][NF]){
  #pragma unroll
  for (int f=0;f<NF;f++) acc[f] = (f32x4){0.f,0.f,0.f,0.f};
  const u8* wp = Wt + ((size_t)g*NW + nbase + r16)*8;
  #pragma unroll
  for (int s=0; s<KSTEPS; s++){
    if (s+5 < KSTEPS){
      int ss5 = (s + 5 + rot) & (KSTEPS-1);
      const u8* wn = wp + (size_t)ss5*4*NW*8;
      #pragma unroll
      for (int f=0; f<NF; f++)
        bb[(s+5)%6][f] = *(const long*)&wn[(size_t)f*128];
    }
    int ss = (s + rot) & (KSTEPS-1);
    long a = *(const long*)&zin[(ss*4+g)*128 + r16*8];
    #pragma unroll
    for (int f=0; f<NF; f++)
      acc[f] = __builtin_amdgcn_mfma_f32_16x16x32_fp8_fp8(a, bb[s%6][f], acc[f],0,0,0);
  }
}

__global__ __launch_bounds__(1024,4) void layer_k(LayerP p){
  __shared__ __align__(16) u8 sZ[2][8192];   // 16 rows x 512 cols, k8-tiled, fp8
  __shared__ float4 psum[16][32];    // h rows — persists to bwdF (proven in R5)
  __shared__ float4 psumC[16][32];   // chunk partial sums
  const int tid = threadIdx.x;
  const int w = tid >> 6, lane = tid & 63;   // w: 0..15
  const int r16 = lane & 15, g = lane >> 4;
  const int rb = blockIdx.x;                 // rows rb*16 .. rb*16+15
  const int nb = w*32;                       // 32-col slice per wave
  const int rot = (rb >> 3) & 15;

  long bb[6][2];

  // earliest: fwd1 weight prefetch + v register prefetch + epilogue scalars.
  // h comes from psum (LDS) in bwdF — no global h re-read.
  wpre<8,512,2>(p.W0T, nb, r16, g, rot, bb);
  float vr[4] = {0.f,0.f,0.f,0.f};
  float im = 0.f, fac = 0.f;
  if (w < 8){
    const int col = w*16 + r16;
    if (!p.first){
      #pragma unroll
      for (int j=0;j<4;j++)
        vr[j] = p.v[((size_t)rb*16 + g*4 + j)*128 + col];
    }
    im  = INV6/(softplus_f(p.rawm[0]) + 0.001f);   // fold fp8 decode into im
    fac = 1.0f/(1.0f + softplus_f(p.rawg[0]));
  }

  // ---- prologue (waves 0..7): cumulative mean -> sZ[0] = [fp8(SZC*xi)|fp8(SZC*h)] ----
  if (tid < 512){
    const int row = tid >> 5;                // 0..15
    const int lane32 = tid & 31;
    const int b = rb >> 5, c = rb & 31;
    const float4* S4 = (const float4*)(p.Sprev + (size_t)b*32*128) + lane32;
    float4 part = {0.f,0.f,0.f,0.f};
    if (row < c){
      float4 t = S4[(size_t)row*32];
      part.x+=t.x; part.y+=t.y; part.z+=t.z; part.w+=t.w;
    }
    if (row+16 < c){
      float4 t = S4[(size_t)(row+16)*32];
      part.x+=t.x; part.y+=t.y; part.z+=t.z; part.w+=t.w;
    }
    float4 myrow = ((const float4*)(p.h + (size_t)rb*16*128))[(size_t)row*32 + lane32];
    psum[row][lane32]  = myrow;
    psumC[row][lane32] = part;
    __syncthreads();
    float4 pfx = {0.f,0.f,0.f,0.f};
    #pragma unroll
    for (int r=0;r<16;r++){
      float4 t = psumC[r][lane32];
      pfx.x+=t.x; pfx.y+=t.y; pfx.z+=t.z; pfx.w+=t.w;
    }
    #pragma unroll
    for (int rr=0; rr<15; rr++){
      float4 t = psum[rr][lane32];
      float sel = rr < row ? 1.0f : 0.0f;
      pfx.x += sel*t.x; pfx.y += sel*t.y; pfx.z += sel*t.z; pfx.w += sel*t.w;
    }
    pfx.x+=myrow.x; pfx.y+=myrow.y; pfx.z+=myrow.z; pfx.w+=myrow.w;
    float inv32 = SZC/(float)(c*16 + row + 1);
    const int d0 = lane32*4;
    unsigned ux = pk4_fp8(pfx.x*inv32, pfx.y*inv32, pfx.z*inv32, pfx.w*inv32);
    unsigned uh = pk4_fp8(myrow.x*SZC, myrow.y*SZC, myrow.z*SZC, myrow.w*SZC);
    *(unsigned*)&sZ[0][(d0>>3)*128      + row*8 + (d0&7)] = ux;   // xi cols 0..127
    *(unsigned*)&sZ[0][(16+(d0>>3))*128 + row*8 + (d0&7)] = uh;   // h  cols 128..255
  } else {
    __syncthreads();                         // match prologue's barrier
  }
  __syncthreads();

  f32x4 acc[2];
  unsigned g1p[2][2], g2p[2][2];

  // fwd1: Zc @ W0 (K=256) -> z1 (sZ[1]), g1 packed
  gphase<8,512,2>(p.W0T, sZ[0], nb, r16, g, rot, acc, bb);
  wpre<16,512,2>(p.W1T, nb, r16, g, rot, bb);
  #pragma unroll
  for (int f=0; f<2; f++){
    int n = nb + f*16 + r16;
    float bias = p.b0[n];
    #pragma unroll
    for (int jp=0; jp<2; jp++){
      float z0, dz0, z1v, dz1;
      gelu_pair(acc[f][2*jp]*INV1   + bias, z0,  dz0);
      gelu_pair(acc[f][2*jp+1]*INV1 + bias, z1v, dz1);
      g1p[f][jp] = pack2bf(dz0, dz1);
      sZ[1][(n>>3)*128 + (g*4+2*jp)*8   + (n&7)] = f2fp8(z0*SZ1);
      sZ[1][(n>>3)*128 + (g*4+2*jp+1)*8 + (n&7)] = f2fp8(z1v*SZ1);
    }
  }
  __syncthreads();

  // fwd2: z1 @ W1 -> z2 (sZ[0]), g2 packed
  gphase<16,512,2>(p.W1T, sZ[1], nb, r16, g, rot, acc, bb);
  wpre<16,512,2>(p.W2T, nb, r16, g, rot, bb);
  #pragma unroll
  for (int f=0; f<2; f++){
    int n = nb + f*16 + r16;
    float bias = p.b1[n];
    #pragma unroll
    for (int jp=0; jp<2; jp++){
      float z0, dz0, z1v, dz1;
      gelu_pair(acc[f][2*jp]*INV2   + bias, z0,  dz0);
      gelu_pair(acc[f][2*jp+1]*INV2 + bias, z1v, dz1);
      g2p[f][jp] = pack2bf(dz0, dz1);
      sZ[0][(n>>3)*128 + (g*4+2*jp)*8   + (n&7)] = f2fp8(z0*SZ2);
      sZ[0][(n>>3)*128 + (g*4+2*jp+1)*8 + (n&7)] = f2fp8(z1v*SZ2);
    }
  }
  __syncthreads();

  // fwd3: z2 @ W2 -> gp3 = W3*gelu'(pre3) (sZ[1])
  gphase<16,512,2>(p.W2T, sZ[0], nb, r16, g, rot, acc, bb);
  wpre<16,512,2>(p.W2b, nb, r16, g, rot, bb);
  #pragma unroll
  for (int f=0; f<2; f++){
    int n = nb + f*16 + r16;
    float bias = p.b2[n];
    float w3s = p.W3[n]*SG3;
    #pragma unroll
    for (int j=0;j<4;j++){
      float xx = acc[f][j]*INV3 + bias;
      sZ[1][(n>>3)*128 + (g*4+j)*8 + (n&7)] = f2fp8(w3s*dgelu_f(xx));
    }
  }
  __syncthreads();

  // bwd2: gp2 = (gp3 @ W2b) * g2 (sZ[0])
  gphase<16,512,2>(p.W2b, sZ[1], nb, r16, g, rot, acc, bb);
  wpre<16,512,2>(p.W1b, nb, r16, g, rot, bb);
  #pragma unroll
  for (int f=0; f<2; f++){
    int n = nb + f*16 + r16;
    #pragma unroll
    for (int jp=0; jp<2; jp++){
      float gv0 = unp_lo(g2p[f][jp]), gv1 = unp_hi(g2p[f][jp]);
      sZ[0][(n>>3)*128 + (g*4+2*jp)*8   + (n&7)] = f2fp8(acc[f][2*jp]*gv0*EN4);
      sZ[0][(n>>3)*128 + (g*4+2*jp+1)*8 + (n&7)] = f2fp8(acc[f][2*jp+1]*gv1*EN4);
    }
  }
  __syncthreads();

  // bwd1: gp1 = (gp2 @ W1b) * g1 (sZ[1])
  gphase<16,512,2>(p.W1b, sZ[0], nb, r16, g, rot, acc, bb);
  long bbF[6][1];
  if (w < 8) wpre<16,128,1>(p.W0h, w*16, r16, g, rot, bbF);
  #pragma unroll
  for (int f=0; f<2; f++){
    int n = nb + f*16 + r16;
    #pragma unroll
    for (int jp=0; jp<2; jp++){
      float gv0 = unp_lo(g1p[f][jp]), gv1 = unp_hi(g1p[f][jp]);
      sZ[1][(n>>3)*128 + (g*4+2*jp)*8   + (n&7)] = f2fp8(acc[f][2*jp]*gv0*EN5);
      sZ[1][(n>>3)*128 + (g*4+2*jp+1)*8 + (n&7)] = f2fp8(acc[f][2*jp+1]*gv1*EN5);
    }
  }
  __syncthreads();

  // bwdF (waves 0..7): gradh = gp1 @ W0h (N=128); v from registers, h from psum
  // (LDS, staged in prologue); dead stores via first/last.
  if (w < 8){
    f32x4 accF[1];
    gphase<16,128,1>(p.W0h, sZ[1], w*16, r16, g, rot, accF, bbF);
    int col = w*16 + r16;
    float hs = 0.f;
    #pragma unroll
    for (int j=0;j<4;j++){
      int row = g*4 + j;
      size_t o = ((size_t)rb*16 + row)*128 + col;
      float hold = ((const float*)psum)[row*128 + col];
      float nv = (vr[j] - accF[0][j]*im)*fac;   // f = -gradh
      float nh = hold + nv;
      if (!p.last){ p.v[o] = nv; p.h[o] = nh; }
      else        { p.hbf[o] = __float2bfloat16(nh); }
      hs += nh;
    }
    if (!p.last){
      hs += __shfl_xor(hs, 16);
      hs += __shfl_xor(hs, 32);
      if (g==0) p.Snext[(size_t)rb*128 + col] = hs;
    }
  }
}

// ---------------- logits: out = hbf(4096x128) @ Ebf(50257x128)^T, fp32 ----------------
// R10 config (best): 128x128 tile, cached stores, n-MAJOR tile order within each
// XCD slice (1572 = 4 mt x 393 nt): co-resident blocks sweep consecutive nt
// stripes of the same 128 rows -> fill-like HBM write page locality.
__global__ __launch_bounds__(256,4) void logits_k(const __hip_bfloat16* __restrict__ A,
                                                  const __hip_bfloat16* __restrict__ Bt,
                                                  float* __restrict__ out){
  constexpr int V = 50257;
  __shared__ __align__(16) __hip_bfloat16 sA[128*64];
  __shared__ __align__(16) __hip_bfloat16 sB[128*64];
  const int tid = threadIdx.x, lane = tid & 63, wave = tid >> 6;
  const int wg = ((blockIdx.x & 7) * 1572) + (blockIdx.x >> 3);
  const int mt = wg / 393, nt = wg % 393;   // n-major within XCD slice
  const int m0 = mt*128, n0 = nt*128;
  const int wm = (wave>>1)*64, wn = (wave&1)*64;
  const int r16 = lane & 15, g = lane >> 4;
  const int srow = tid >> 3;
  const int scol = ((tid & 7) ^ (srow & 7)) * 8;
  const int sx = (r16 & 7) * 8;
  f32x4 zero = {0.f,0.f,0.f,0.f};
  f32x4 acc[4][4];   // [tb (n-subtile)][ta (m-subtile)]
  #pragma unroll
  for (int i=0;i<4;i++){ acc[i][0]=zero; acc[i][1]=zero; acc[i][2]=zero; acc[i][3]=zero; }

  auto stageA = [&](int ks){
    #pragma unroll
    for (int i=0;i<4;i++)
      gload_lds16(A + (size_t)(m0 + i*32 + srow)*128 + ks*64 + scol,
                  &sA[i*2048 + wave*512]);
  };
  auto stageB = [&](int ks){
    #pragma unroll
    for (int i=0;i<4;i++){
      int r = n0 + i*32 + srow; if (r > V-1) r = V-1;
      gload_lds16(Bt + (size_t)r*128 + ks*64 + scol,
                  &sB[i*2048 + wave*512]);
    }
  };
  stageA(0); stageB(0);
  __syncthreads();
  #pragma unroll
  for (int ks=0; ks<2; ks++){
    #pragma unroll
    for (int kk=0; kk<2; kk++){
      const int ko = kk*32 + g*8;
      short8 a[4], b[4];
      #pragma unroll
      for (int ti=0; ti<4; ti++) a[ti] = *(const short8*)&sA[(wm + ti*16 + r16)*64 + (ko ^ sx)];
      #pragma unroll
      for (int tj=0; tj<4; tj++) b[tj] = *(const short8*)&sB[(wn + tj*16 + r16)*64 + (ko ^ sx)];
      #pragma unroll
      for (int tb=0; tb<4; tb++)
        #pragma unroll
        for (int ta=0; ta<4; ta++)
          acc[tb][ta] = __builtin_amdgcn_mfma_f32_16x16x32_bf16(b[tb],a[ta],acc[tb][ta],0,0,0);
    }
    if (ks==0){
      __syncthreads();          // all reads of step-0 tile done
      stageA(1); stageB(1);
      __syncthreads();          // step-1 tile landed
    }
  }
  #pragma unroll
  for (int tb=0; tb<4; tb++){
    #pragma unroll
    for (int ta=0; ta<4; ta++){
      int row = m0 + wm + ta*16 + r16;
      int n   = n0 + wn + tb*16 + g*4;
      f32x4 c = acc[tb][ta];
      float* po = out + (size_t)row*V + n;
      if (n + 3 < V){
        store_f4_a4(po, c);
      } else {
        #pragma unroll
        for (int j=0;j<4;j++) if (n+j < V) po[j] = c[j];
      }
    }
  }
}

extern "C" void kernel_launch(void* const* d_in, const int* in_sizes, int n_in,
                              void* d_out, int out_size, void* d_ws, size_t ws_size,
                              hipStream_t stream){
  const int*   x    = (const int*)  d_in[0];
  const float* E    = (const float*)d_in[1];
  const float* P    = (const float*)d_in[2];
  const float* W0   = (const float*)d_in[3];
  const float* b0   = (const float*)d_in[4];
  const float* W1   = (const float*)d_in[5];
  const float* b1   = (const float*)d_in[6];
  const float* W2   = (const float*)d_in[7];
  const float* b2   = (const float*)d_in[8];
  const float* W3   = (const float*)d_in[9];
  const float* rawm = (const float*)d_in[11];
  const float* rawg = (const float*)d_in[12];

  constexpr int B=8, T=512, D=128, V=50257, L=8;
  const int M = B*T;                       // 4096

  char* w = (char*)d_ws;
  auto alloc = [&](size_t bytes)->char*{ char* r = w; w += (bytes + 255) & ~(size_t)255; return r; };
  float* h            = (float*)alloc((size_t)M*D*4);
  float* v            = (float*)alloc((size_t)M*D*4);
  __hip_bfloat16* hbf = (__hip_bfloat16*)alloc((size_t)M*D*2);
  float* S0           = (float*)alloc((size_t)B*32*128*4);
  float* S1           = (float*)alloc((size_t)B*32*128*4);
  u8* W0T             = (u8*)alloc((size_t)131072);
  u8* W1T             = (u8*)alloc((size_t)262144);
  u8* W2T             = (u8*)alloc((size_t)262144);
  u8* W2b             = (u8*)alloc((size_t)262144);
  u8* W1b             = (u8*)alloc((size_t)262144);
  u8* W0h             = (u8*)alloc((size_t)65536);
  __hip_bfloat16* Ebf = (__hip_bfloat16*)alloc((size_t)V*D*2);

  SetupP sp{};
  sp.x=x; sp.E=E; sp.P=P; sp.h=h; sp.S=S0;
  sp.W0=W0; sp.W1=W1; sp.W2=W2;
  sp.W0T=W0T; sp.W1T=W1T; sp.W2T=W2T; sp.W2b=W2b; sp.W1b=W1b; sp.W0h=W0h;
  sp.Ebf=Ebf;
  setup_k<<<5830, 512, 0, stream>>>(sp);

  LayerP lp{};
  lp.W0T=W0T; lp.W1T=W1T; lp.W2T=W2T; lp.W2b=W2b; lp.W1b=W1b; lp.W0h=W0h;
  lp.b0=b0; lp.b1=b1; lp.b2=b2; lp.W3=W3;
  lp.v=v; lp.h=h; lp.hbf=hbf; lp.rawm=rawm; lp.rawg=rawg;

  for (int l=0; l<L; l++){
    lp.Sprev = (l&1) ? S1 : S0;
    lp.Snext = (l&1) ? S0 : S1;
    lp.first = (l==0) ? 1 : 0;
    lp.last  = (l==L-1) ? 1 : 0;
    layer_k<<<M/16, 1024, 0, stream>>>(lp);
  }
  logits_k<<<12576, 256, 0, stream>>>(hbf, Ebf, (float*)d_out);
}